// Round 4
// baseline (8978.851 us; speedup 1.0000x reference)
//
#include <hip/hip_runtime.h>
#include <math.h>

// Problem dims (fixed by setup_inputs)
#define MTOK 4096
#define DDIM 1024
#define NEXP 16
#define PSLOT 1024
#define NPDIM 16384   // NEXP*PSLOT
#define HDIM 1365

#define BM 64
#define BN 64
#define BK 16

typedef unsigned short u16;  // raw bf16

__device__ __forceinline__ float b2f(u16 v) {
    union { unsigned int u; float f; } x;
    x.u = ((unsigned int)v) << 16;
    return x.f;
}
__device__ __forceinline__ u16 f2b(float f) {
    union { float f; unsigned int u; } x;
    x.f = f;
    unsigned int r = x.u + 0x7FFFu + ((x.u >> 16) & 1u);  // RTNE
    return (u16)(r >> 16);
}
__device__ __forceinline__ float ldv(const float* p, long long i) { return p[i]; }
__device__ __forceinline__ float ldv(const u16*  p, long long i) { return b2f(p[i]); }
__device__ __forceinline__ void stv(float* p, long long i, float v) { p[i] = v; }
__device__ __forceinline__ void stv(u16*  p, long long i, float v) { p[i] = f2b(v); }

// ---------------------------------------------------------------------------
// Bounds-checked GEMM, mixed dtypes (fp32/bf16 in, fp32/bf16 out), fp32 accum:
//   C[M,N] = op(A) * B  (+bias)(relu)(*rowsc)
//   TRANSA=false: A is [M,K] row-major. TRANSA=true: A is [K,M] row-major,
//   optional fp32 scale S[k,i] applied while staging.
//   B is [K,N] row-major. blockIdx.z batches via sA/sB/sC/sBias offsets.
// 256 threads; 64x64 tile; 4x4 micro-tile per thread.
// ---------------------------------------------------------------------------
template<typename TA, typename TB, typename TC,
         bool TRANSA, bool ASCALE, bool BIASF, bool RELUF, bool ROWSC>
__global__ __launch_bounds__(256) void gemm_k(
    const TA* __restrict__ A, long long sA, int lda,
    const TB* __restrict__ B, long long sB, int ldb,
    TC* __restrict__ C, long long sC, int ldc,
    const float* __restrict__ S, int lds_,
    const float* __restrict__ bias, int sBias,
    const float* __restrict__ rowsc,
    int M, int N, int K)
{
    __shared__ float As[BK][BM + 4];
    __shared__ float Bs[BK][BN + 4];

    const int bz = blockIdx.z;
    A += (long long)bz * sA;
    B += (long long)bz * sB;
    C += (long long)bz * sC;
    const float* biasp = BIASF ? (bias + (long long)bz * sBias) : nullptr;

    const int row0 = blockIdx.y * BM;
    const int col0 = blockIdx.x * BN;
    const int tid = threadIdx.x;
    const int tx = tid & 15;   // column group
    const int ty = tid >> 4;   // row group

    float acc[4][4];
#pragma unroll
    for (int i = 0; i < 4; ++i)
#pragma unroll
        for (int j = 0; j < 4; ++j) acc[i][j] = 0.f;

    for (int k0 = 0; k0 < K; k0 += BK) {
        // ---- stage A tile -> As[k][i]
        if (TRANSA) {
#pragma unroll
            for (int it = 0; it < 4; ++it) {
                int k = (tid >> 6) + it * 4;   // 0..15
                int i = tid & 63;              // 0..63
                int gk = k0 + k, gi = row0 + i;
                float v = 0.f;
                if (gk < K && gi < M) {
                    v = ldv(A, (long long)gk * lda + gi);
                    if (ASCALE) v *= S[(long long)gk * lds_ + gi];
                }
                As[k][i] = v;
            }
        } else {
#pragma unroll
            for (int it = 0; it < 4; ++it) {
                int i = (tid >> 4) + it * 16;  // 0..63
                int k = tid & 15;              // 0..15
                int gi = row0 + i, gk = k0 + k;
                float v = 0.f;
                if (gi < M && gk < K) v = ldv(A, (long long)gi * lda + gk);
                As[k][i] = v;
            }
        }
        // ---- stage B tile -> Bs[k][j]
#pragma unroll
        for (int it = 0; it < 4; ++it) {
            int k = (tid >> 6) + it * 4;
            int j = tid & 63;
            int gk = k0 + k, gj = col0 + j;
            float v = 0.f;
            if (gk < K && gj < N) v = ldv(B, (long long)gk * ldb + gj);
            Bs[k][j] = v;
        }
        __syncthreads();

#pragma unroll
        for (int k = 0; k < BK; ++k) {
            float4 a4 = *(const float4*)&As[k][ty * 4];
            float4 b4 = *(const float4*)&Bs[k][tx * 4];
            float a[4] = {a4.x, a4.y, a4.z, a4.w};
            float b[4] = {b4.x, b4.y, b4.z, b4.w};
#pragma unroll
            for (int i = 0; i < 4; ++i)
#pragma unroll
                for (int j = 0; j < 4; ++j)
                    acc[i][j] = fmaf(a[i], b[j], acc[i][j]);
        }
        __syncthreads();
    }

    // ---- epilogue
#pragma unroll
    for (int i = 0; i < 4; ++i) {
        int gi = row0 + ty * 4 + i;
        if (gi >= M) continue;
        float rs = ROWSC ? rowsc[gi] : 1.f;
#pragma unroll
        for (int j = 0; j < 4; ++j) {
            int gj = col0 + tx * 4 + j;
            if (gj >= N) continue;
            float v = acc[i][j];
            if (BIASF) v += biasp[gj];
            if (RELUF) v = fmaxf(v, 0.f);
            if (ROWSC) v *= rs;
            stv(C, (long long)gi * ldc + gj, v);
        }
    }
}

// ---------------------------------------------------------------------------
// Softmax pass over bf16 logits: L[m,:] -> E = exp(L - rowmax) in place (bf16);
//   rsc[m] = 1/sum(E);  rsd[m,p] = 1/sum_n E[m, n*P + p]   (fp32 outputs)
// One block (256 thr) per token row.
// ---------------------------------------------------------------------------
__global__ __launch_bounds__(256) void softmax_k(
    u16* __restrict__ L, float* __restrict__ rsd, float* __restrict__ rsc)
{
    const int m = blockIdx.x;
    u16* row = L + (long long)m * NPDIM;
    const int tid = threadIdx.x;
    __shared__ float red[256];

    // max
    float mx = -1e30f;
    for (int i = tid; i < NPDIM; i += 256) mx = fmaxf(mx, b2f(row[i]));
    red[tid] = mx;
    __syncthreads();
    for (int s = 128; s > 0; s >>= 1) {
        if (tid < s) red[tid] = fmaxf(red[tid], red[tid + s]);
        __syncthreads();
    }
    const float mxAll = red[0];
    __syncthreads();

    // exp (store rounded bf16), sum the ROUNDED values for consistency
    float sum = 0.f;
    for (int i = tid; i < NPDIM; i += 256) {
        float e = __expf(b2f(row[i]) - mxAll);
        u16 eb = f2b(e);
        row[i] = eb;
        sum += b2f(eb);
    }
    red[tid] = sum;
    __syncthreads();
    for (int s = 128; s > 0; s >>= 1) {
        if (tid < s) red[tid] += red[tid + s];
        __syncthreads();
    }
    if (tid == 0) rsc[m] = 1.f / red[0];
    __syncthreads();

    // per-slot expert sums (over the rounded E)
    for (int p = tid; p < PSLOT; p += 256) {
        float s = 0.f;
#pragma unroll
        for (int n = 0; n < NEXP; ++n) s += b2f(row[n * PSLOT + p]);
        rsd[(long long)m * PSLOT + p] = 1.f / s;
    }
}

extern "C" void kernel_launch(void* const* d_in, const int* in_sizes, int n_in,
                              void* d_out, int out_size, void* d_ws, size_t ws_size,
                              hipStream_t stream)
{
    // All inputs float32 (reference dtypes); output float32 (reference output dtype).
    const float* x   = (const float*)d_in[0];  // [4096,1024]
    const float* phi = (const float*)d_in[1];  // [1024,16,1024]
    const float* W1  = (const float*)d_in[2];  // [16,1024,1365]
    const float* b1  = (const float*)d_in[3];  // [16,1365]
    const float* W2  = (const float*)d_in[4];  // [16,1365,1024]
    const float* b2  = (const float*)d_in[5];  // [16,1024]
    float* Y = (float*)d_out;                  // [4096,1024] fp32

    // Workspace: bf16 intermediates, ~253 MB total (proven in-bounds in R2/R3).
    char* w = (char*)d_ws;
    u16*   L   = (u16*)w;   w += (size_t)MTOK * NPDIM * 2;          // 128 MB (logits -> E)
    float* rsd = (float*)w; w += (size_t)MTOK * PSLOT * 4;          // 16 MB
    float* rsc = (float*)w; w += (size_t)MTOK * 4;                  // 16 KB
    u16*   Xs  = (u16*)w;   w += (size_t)NEXP * PSLOT * DDIM * 2;   // 32 MB
    u16*   Ys  = (u16*)w;   w += (size_t)NEXP * PSLOT * PSLOT * 2;  // 32 MB
    u16*   Hb  = (u16*)w;   w += (size_t)NEXP * PSLOT * HDIM * 2;   // 44.7 MB

    // 1) logits: L = x @ phi   [4096,16384], K=1024
    gemm_k<float,float,u16,false,false,false,false,false><<<dim3(NPDIM/BN, MTOK/BM, 1), 256, 0, stream>>>(
        x, 0, DDIM,  phi, 0, NPDIM,  L, 0, NPDIM,
        nullptr, 0, nullptr, 0, nullptr, MTOK, NPDIM, DDIM);

    // 2) E = exp(L - max) in place, rsd, rsc
    softmax_k<<<dim3(MTOK), 256, 0, stream>>>(L, rsd, rsc);

    // 3) Xs[n][p,d] = sum_m (E*rsd)[m, n*P+p] * x[m,d]   (TN, K=4096)
    gemm_k<u16,float,u16,true,true,false,false,false><<<dim3(DDIM/BN, PSLOT/BM, NEXP), 256, 0, stream>>>(
        L, PSLOT /*column offset per expert*/, NPDIM,
        x, 0, DDIM,
        Xs, (long long)PSLOT * DDIM, DDIM,
        rsd, PSLOT, nullptr, 0, nullptr, PSLOT, DDIM, MTOK);

    // 4) H = relu(Xs @ W1 + b1)   per expert: [1024,1365], K=1024
    gemm_k<u16,float,u16,false,false,true,true,false><<<dim3((HDIM + BN - 1)/BN, PSLOT/BM, NEXP), 256, 0, stream>>>(
        Xs, (long long)PSLOT * DDIM, DDIM,
        W1, (long long)DDIM * HDIM, HDIM,
        Hb, (long long)PSLOT * HDIM, HDIM,
        nullptr, 0, b1, HDIM, nullptr, PSLOT, HDIM, DDIM);

    // 5) Ys = H @ W2 + b2   per expert: [1024,1024], K=1365
    gemm_k<u16,float,u16,false,false,true,false,false><<<dim3(PSLOT/BN, PSLOT/BM, NEXP), 256, 0, stream>>>(
        Hb, (long long)PSLOT * HDIM, HDIM,
        W2, (long long)HDIM * PSLOT, PSLOT,
        Ys, (long long)PSLOT * PSLOT, PSLOT,
        nullptr, 0, b2, PSLOT, nullptr, PSLOT, PSLOT, HDIM);

    // 6) Y[m,o] = rsc[m] * sum_k E[m,k] * Ysflat[k,o]   [4096,1024], K=16384  (fp32 out)
    gemm_k<u16,u16,float,false,false,false,false,true><<<dim3(PSLOT/BN, MTOK/BM, 1), 256, 0, stream>>>(
        L, 0, NPDIM,
        Ys, 0, PSLOT,
        Y, 0, PSLOT,
        nullptr, 0, nullptr, 0, rsc, MTOK, PSLOT, NPDIM);
}

// Round 5
// 3247.987 us; speedup vs baseline: 2.7644x; 2.7644x over previous
//
#include <hip/hip_runtime.h>
#include <math.h>

// Problem dims (fixed by setup_inputs)
#define MTOK 4096
#define DDIM 1024
#define NEXP 16
#define PSLOT 1024
#define NPDIM 16384   // NEXP*PSLOT
#define HDIM 1365
#define HPAD 1376     // HDIM rounded to multiple of 32 (K-tile), 16B-aligned rows

typedef unsigned short u16;  // raw bf16
typedef __attribute__((ext_vector_type(8))) short short8;     // MFMA A/B frag (8 bf16)
typedef __attribute__((ext_vector_type(8))) unsigned short ushort8;
typedef __attribute__((ext_vector_type(4))) float f32x4;      // MFMA C/D frag

__device__ __forceinline__ float b2f(u16 v) {
    union { unsigned int u; float f; } x;
    x.u = ((unsigned int)v) << 16;
    return x.f;
}
__device__ __forceinline__ u16 f2b(float f) {
    union { float f; unsigned int u; } x;
    x.f = f;
    unsigned int r = x.u + 0x7FFFu + ((x.u >> 16) & 1u);  // RTNE
    return (u16)(r >> 16);
}
__device__ __forceinline__ float ldv(const float* p, long long i) { return p[i]; }
__device__ __forceinline__ float ldv(const u16*  p, long long i) { return b2f(p[i]); }
__device__ __forceinline__ void stv(float* p, long long i, float v) { p[i] = v; }
__device__ __forceinline__ void stv(u16*  p, long long i, float v) { p[i] = f2b(v); }

// ---------------------------------------------------------------------------
// MFMA GEMM: C[M,N] = A' * B (+bias)(relu)(*rowsc), fp32 accumulate.
//   AMODE 0: A is bf16 [M,K] row-major -> global_load_lds (dims must be exact)
//   AMODE 1: A is fp32 [M,K] row-major -> convert-in-staging
//   AMODE 2: A is bf16 [K,M] row-major (logical A^T), scaled by S[k][col&1023]
//   B is [K,N] row-major (fp32 or bf16), transpose-staged to Bs[n][k].
//   Staging bound-checks B against (Kb, Nb) with zero-fill.
//   Epilogue: col<N -> value; N<=col<NZ -> 0 (pad-zeroing); col>=NZ skip.
// 256 threads, 128x128 tile, BK=32, 4 waves (2x2), 4x4 16x16x32 frags/wave.
// ---------------------------------------------------------------------------
template<int AMODE, typename TA, typename TB, typename TC,
         bool BIASF, bool RELUF, bool ROWSC>
__global__ __launch_bounds__(256) void mgemm(
    const TA* __restrict__ A, long long sA, int lda,
    const TB* __restrict__ B, long long sB, int ldb,
    TC* __restrict__ C, long long sC, int ldc,
    const float* __restrict__ S,
    const float* __restrict__ bias, long long sBias,
    const float* __restrict__ rowsc,
    int M, int N, int NZ, int K, int Kb, int Nb)
{
    constexpr int AS = (AMODE == 0) ? 32 : 40;  // As row stride (elements)
    constexpr int BS = 40;                      // Bs row stride (elements)
    __shared__ u16 As[128 * AS];
    __shared__ u16 Bs[128 * BS];

    const int bz = blockIdx.z;
    A += (long long)bz * sA;
    B += (long long)bz * sB;
    C += (long long)bz * sC;
    const float* biasp = BIASF ? (bias + (long long)bz * sBias) : nullptr;

    const int m0 = blockIdx.y * 128;
    const int n0 = blockIdx.x * 128;
    const int tid  = threadIdx.x;
    const int lane = tid & 63;
    const int wv   = tid >> 6;       // wave 0..3
    const int wm   = wv & 1;         // wave row (2x2)
    const int wn   = wv >> 1;        // wave col
    const int quad = lane >> 4;
    const int l16  = lane & 15;

    f32x4 acc[4][4];
#pragma unroll
    for (int i = 0; i < 4; ++i)
#pragma unroll
        for (int j = 0; j < 4; ++j) acc[i][j] = (f32x4){0.f, 0.f, 0.f, 0.f};

    for (int k0 = 0; k0 < K; k0 += 32) {
        // ---------------- stage A -> As[m][k] ----------------
        if constexpr (AMODE == 0) {
            // direct-to-LDS DMA: rows 64B, dest = wave-uniform base + lane*16
#pragma unroll
            for (int q = 0; q < 2; ++q) {
                const u16* gp = A + (long long)(m0 + wv * 32 + q * 16 + (lane >> 2)) * lda
                                  + k0 + (lane & 3) * 8;
                u16* lp = &As[(wv * 32 + q * 16) * 32];  // wave-uniform
                __builtin_amdgcn_global_load_lds(
                    (const __attribute__((address_space(1))) unsigned int*)gp,
                    (__attribute__((address_space(3))) unsigned int*)lp, 16, 0, 0);
            }
        } else if constexpr (AMODE == 1) {
            // fp32 [M,K]: thread covers row m, 16 consecutive k
            const int m = tid >> 1, h = tid & 1;
            const TA* gp = A + (long long)(m0 + m) * lda + k0 + h * 16;
            ushort8 v0, v1;
#pragma unroll
            for (int j = 0; j < 8; ++j) v0[j] = f2b((float)gp[j]);
#pragma unroll
            for (int j = 0; j < 8; ++j) v1[j] = f2b((float)gp[8 + j]);
            *(ushort8*)&As[m * AS + h * 16]     = v0;
            *(ushort8*)&As[m * AS + h * 16 + 8] = v1;
        } else {
            // bf16 [K,M] + scale: thread patch = 8(k) x 2(m)
            const int o = tid >> 6, p = tid & 63;
            const int mloc = 2 * p;
            ushort8 va, vb;
#pragma unroll
            for (int i = 0; i < 8; ++i) {
                const long long kg = k0 + o * 8 + i;
                const u16* ep = (const u16*)A + kg * lda + (m0 + mloc);
                const float s0 = S[kg * 1024 + ((m0 + mloc) & 1023)];
                const float s1 = S[kg * 1024 + ((m0 + mloc + 1) & 1023)];
                va[i] = f2b(b2f(ep[0]) * s0);
                vb[i] = f2b(b2f(ep[1]) * s1);
            }
            *(ushort8*)&As[mloc * AS + o * 8]       = va;
            *(ushort8*)&As[(mloc + 1) * AS + o * 8] = vb;
        }

        // ---------------- stage B [K,N] -> Bs[n][k] ----------------
        {
            const int o = tid >> 6, p = tid & 63;
            const int nloc = 2 * p;
            const int ng0 = n0 + nloc, ng1 = ng0 + 1;
            ushort8 va, vb;
#pragma unroll
            for (int i = 0; i < 8; ++i) {
                const int kg = k0 + o * 8 + i;
                float v0 = 0.f, v1 = 0.f;
                if (kg < Kb) {
                    if (ng0 < Nb) v0 = ldv(B, (long long)kg * ldb + ng0);
                    if (ng1 < Nb) v1 = ldv(B, (long long)kg * ldb + ng1);
                }
                va[i] = f2b(v0);
                vb[i] = f2b(v1);
            }
            *(ushort8*)&Bs[nloc * BS + o * 8]       = va;
            *(ushort8*)&Bs[(nloc + 1) * BS + o * 8] = vb;
        }
        __syncthreads();

        // ---------------- MFMA ----------------
        short8 bfr[4];
#pragma unroll
        for (int ni = 0; ni < 4; ++ni)
            bfr[ni] = *(const short8*)&Bs[(wn * 64 + ni * 16 + l16) * BS + quad * 8];
#pragma unroll
        for (int mi = 0; mi < 4; ++mi) {
            short8 a = *(const short8*)&As[(wm * 64 + mi * 16 + l16) * AS + quad * 8];
#pragma unroll
            for (int ni = 0; ni < 4; ++ni)
                acc[mi][ni] = __builtin_amdgcn_mfma_f32_16x16x32_bf16(a, bfr[ni], acc[mi][ni], 0, 0, 0);
        }
        __syncthreads();
    }

    // ---------------- epilogue ----------------
#pragma unroll
    for (int mi = 0; mi < 4; ++mi) {
#pragma unroll
        for (int r = 0; r < 4; ++r) {
            const int rg = m0 + wm * 64 + mi * 16 + quad * 4 + r;
            if (rg >= M) continue;
            const float rs = ROWSC ? rowsc[rg] : 1.f;
#pragma unroll
            for (int ni = 0; ni < 4; ++ni) {
                const int cg = n0 + wn * 64 + ni * 16 + l16;
                if (cg < N) {
                    float v = acc[mi][ni][r];
                    if (BIASF) v += biasp[cg];
                    if (RELUF) v = fmaxf(v, 0.f);
                    if (ROWSC) v *= rs;
                    stv(C, (long long)rg * ldc + cg, v);
                } else if (cg < NZ) {
                    stv(C, (long long)rg * ldc + cg, 0.f);  // zero K-pad cols
                }
            }
        }
    }
}

// ---------------------------------------------------------------------------
// Softmax pass over bf16 logits: L[m,:] -> E = exp(L - rowmax) in place (bf16);
//   rsc[m] = 1/sum(E);  rsd[m,p] = 1/sum_n E[m, n*P + p]   (fp32 outputs)
// ---------------------------------------------------------------------------
__global__ __launch_bounds__(256) void softmax_k(
    u16* __restrict__ L, float* __restrict__ rsd, float* __restrict__ rsc)
{
    const int m = blockIdx.x;
    u16* row = L + (long long)m * NPDIM;
    const int tid = threadIdx.x;
    __shared__ float red[256];

    float mx = -1e30f;
    for (int i = tid; i < NPDIM; i += 256) mx = fmaxf(mx, b2f(row[i]));
    red[tid] = mx;
    __syncthreads();
    for (int s = 128; s > 0; s >>= 1) {
        if (tid < s) red[tid] = fmaxf(red[tid], red[tid + s]);
        __syncthreads();
    }
    const float mxAll = red[0];
    __syncthreads();

    float sum = 0.f;
    for (int i = tid; i < NPDIM; i += 256) {
        float e = __expf(b2f(row[i]) - mxAll);
        u16 eb = f2b(e);
        row[i] = eb;
        sum += b2f(eb);
    }
    red[tid] = sum;
    __syncthreads();
    for (int s = 128; s > 0; s >>= 1) {
        if (tid < s) red[tid] += red[tid + s];
        __syncthreads();
    }
    if (tid == 0) rsc[m] = 1.f / red[0];
    __syncthreads();

    for (int p = tid; p < PSLOT; p += 256) {
        float s = 0.f;
#pragma unroll
        for (int n = 0; n < NEXP; ++n) s += b2f(row[n * PSLOT + p]);
        rsd[(long long)m * PSLOT + p] = 1.f / s;
    }
}

extern "C" void kernel_launch(void* const* d_in, const int* in_sizes, int n_in,
                              void* d_out, int out_size, void* d_ws, size_t ws_size,
                              hipStream_t stream)
{
    const float* x   = (const float*)d_in[0];  // [4096,1024]
    const float* phi = (const float*)d_in[1];  // [1024,16,1024]
    const float* W1  = (const float*)d_in[2];  // [16,1024,1365]
    const float* b1  = (const float*)d_in[3];  // [16,1365]
    const float* W2  = (const float*)d_in[4];  // [16,1365,1024]
    const float* b2  = (const float*)d_in[5];  // [16,1024]
    float* Y = (float*)d_out;                  // [4096,1024] fp32

    // Workspace (~251 MB, same budget as the passing R4 layout)
    char* w = (char*)d_ws;
    u16*   L   = (u16*)w;   w += (size_t)MTOK * NPDIM * 2;          // 128 MB (logits -> E)
    float* rsd = (float*)w; w += (size_t)MTOK * PSLOT * 4;          // 16 MB
    float* rsc = (float*)w; w += (size_t)MTOK * 4;                  // 16 KB
    u16*   Xs  = (u16*)w;   w += (size_t)NEXP * PSLOT * DDIM * 2;   // 32 MB
    u16*   Ys  = (u16*)w;   w += (size_t)NEXP * PSLOT * PSLOT * 2;  // 32 MB
    u16*   Hb  = (u16*)w;   w += (size_t)NEXP * PSLOT * HPAD * 2;   // 45.1 MB

    // 1) L = x @ phi   [4096,16384], K=1024  (fp32 A convert, fp32 B [K,N])
    mgemm<1, float, float, u16, false, false, false>
        <<<dim3(NPDIM / 128, MTOK / 128, 1), 256, 0, stream>>>(
        x, 0, DDIM,  phi, 0, NPDIM,  L, 0, NPDIM,
        nullptr, nullptr, 0, nullptr,
        MTOK, NPDIM, NPDIM, DDIM, DDIM, NPDIM);

    // 2) E = exp(L - max) in place; rsd, rsc
    softmax_k<<<dim3(MTOK), 256, 0, stream>>>(L, rsd, rsc);

    // 3) Xs[np,d] = sum_m (E*rsd)[m,np] * x[m,d]   (A^T staging + scale, K=4096)
    mgemm<2, u16, float, u16, false, false, false>
        <<<dim3(DDIM / 128, NPDIM / 128, 1), 256, 0, stream>>>(
        L, 0, NPDIM,  x, 0, DDIM,  Xs, 0, DDIM,
        rsd, nullptr, 0, nullptr,
        NPDIM, DDIM, DDIM, MTOK, MTOK, DDIM);

    // 4) H = relu(Xs @ W1 + b1) per expert  [1024,1365]->[1024,1376], K=1024
    mgemm<0, u16, float, u16, true, true, false>
        <<<dim3((HPAD + 127) / 128, PSLOT / 128, NEXP), 256, 0, stream>>>(
        Xs, (long long)PSLOT * DDIM, DDIM,
        W1, (long long)DDIM * HDIM, HDIM,
        Hb, (long long)PSLOT * HPAD, HPAD,
        nullptr, b1, HDIM, nullptr,
        PSLOT, HDIM, HPAD, DDIM, DDIM, HDIM);

    // 5) Ys = H @ W2 + b2 per expert  [1024,1024], K=1376 (pad zeros both sides)
    mgemm<0, u16, float, u16, true, false, false>
        <<<dim3(PSLOT / 128, PSLOT / 128, NEXP), 256, 0, stream>>>(
        Hb, (long long)PSLOT * HPAD, HPAD,
        W2, (long long)HDIM * PSLOT, PSLOT,
        Ys, (long long)PSLOT * PSLOT, PSLOT,
        nullptr, b2, PSLOT, nullptr,
        PSLOT, PSLOT, PSLOT, HPAD, HDIM, PSLOT);

    // 6) Y[m,o] = rsc[m] * sum_np E[m,np] * Ys[np,o]   [4096,1024], K=16384
    mgemm<0, u16, u16, float, false, false, true>
        <<<dim3(PSLOT / 128, MTOK / 128, 1), 256, 0, stream>>>(
        L, 0, NPDIM,  Ys, 0, PSLOT,  Y, 0, PSLOT,
        nullptr, nullptr, 0, rsc,
        MTOK, PSLOT, PSLOT, NPDIM, NPDIM, PSLOT);
}